// Round 11
// baseline (252.500 us; speedup 1.0000x reference)
//
#include <hip/hip_runtime.h>
#include <cstdint>
#include <cstddef>

#define DEV __device__ __forceinline__

typedef float f32x4 __attribute__((ext_vector_type(4)));
typedef short bf16x8 __attribute__((ext_vector_type(8)));

DEV unsigned short f2bf(float f) {
  union { float f; unsigned u; } v; v.f = f;
  unsigned u = v.u;
  unsigned r = u + 0x7FFFu + ((u >> 16) & 1u);   // RNE
  return (unsigned short)(r >> 16);
}
DEV float bf2f(unsigned short h) {
  union { unsigned u; float f; } v; v.u = ((unsigned)h) << 16;
  return v.f;
}
DEV unsigned cvtpk(float lo, float hi) {         // 2 f32 -> packed 2x bf16 (RNE)
  unsigned r;
  asm("v_cvt_pk_bf16_f32 %0, %1, %2" : "=v"(r) : "v"(lo), "v"(hi));
  return r;
}

DEV void gload16(const void* g, void* l) {
  __builtin_amdgcn_global_load_lds((const __attribute__((address_space(1))) unsigned int*)g,
                                   (__attribute__((address_space(3))) unsigned int*)l,
                                   16, 0, 0);
}

DEV f32x4 MFMA(bf16x8 a, bf16x8 b, f32x4 c) {
  return __builtin_amdgcn_mfma_f32_16x16x32_bf16(a, b, c, 0, 0, 0);
}

// ---------------- fp32 -> bf16 convert ----------------
__global__ void k_f2bf(const float* __restrict__ src, unsigned short* __restrict__ dst, int n) {
  int i = (blockIdx.x * blockDim.x + threadIdx.x) * 4;
  int stride = gridDim.x * blockDim.x * 4;
  for (; i < n; i += stride) {
    float4 v = *(const float4*)(src + i);
    ushort4 o;
    o.x = f2bf(v.x); o.y = f2bf(v.y); o.z = f2bf(v.z); o.w = f2bf(v.w);
    *(ushort4*)(dst + i) = o;
  }
}

// ---------------- merged weights: M1 = fw[:, :512] @ gw_out ; M2 = fw[:, 512:] @ lw_out ----------------
__global__ __launch_bounds__(256) void k_merge(const float* __restrict__ fw,
                                               const float* __restrict__ gw_out,
                                               const float* __restrict__ lw_out,
                                               unsigned short* __restrict__ M1b,
                                               unsigned short* __restrict__ M2b) {
  __shared__ float Fa[64][68];
  __shared__ float Gb[64][68];
  const int bi = blockIdx.x, bj = blockIdx.y, m2 = blockIdx.z;
  const float* g = m2 ? lw_out : gw_out;
  const int i0 = bi * 64, j0 = bj * 64;
  const int tid = threadIdx.x;
  const int tr = tid >> 4, tc = tid & 15;
  float acc[4][4] = {};
  for (int kc = 0; kc < 8; kc++) {
    int k0 = kc * 64;
    __syncthreads();
    #pragma unroll
    for (int it = 0; it < 4; it++) {
      int r = tr + 16 * it;
      float4 v = *(const float4*)(fw + (size_t)(i0 + r) * 1024 + m2 * 512 + k0 + tc * 4);
      Fa[tc * 4 + 0][r] = v.x; Fa[tc * 4 + 1][r] = v.y;
      Fa[tc * 4 + 2][r] = v.z; Fa[tc * 4 + 3][r] = v.w;
      *(float4*)&Gb[r][tc * 4] = *(const float4*)(g + (size_t)(k0 + r) * 512 + j0 + tc * 4);
    }
    __syncthreads();
    for (int k = 0; k < 64; k++) {
      float4 a4 = *(const float4*)&Fa[k][tr * 4];
      float4 b4 = *(const float4*)&Gb[k][tc * 4];
      float av[4] = {a4.x, a4.y, a4.z, a4.w};
      float bv[4] = {b4.x, b4.y, b4.z, b4.w};
      #pragma unroll
      for (int r = 0; r < 4; r++)
        #pragma unroll
        for (int c = 0; c < 4; c++)
          acc[r][c] += av[r] * bv[c];
    }
  }
  unsigned short* M = m2 ? M2b : M1b;
  #pragma unroll
  for (int r = 0; r < 4; r++) {
    ushort4 pk;
    pk.x = f2bf(acc[r][0]); pk.y = f2bf(acc[r][1]);
    pk.z = f2bf(acc[r][2]); pk.w = f2bf(acc[r][3]);
    *(ushort4*)&M[(size_t)(i0 + tr * 4 + r) * 512 + j0 + tc * 4] = pk;
  }
}

// bias1 = fw1 @ gb_out + fb ; bias2 = fw2 @ lb_out.  grid (8,2), 64 outputs/block.
__global__ __launch_bounds__(256) void k_bias(const float* __restrict__ fw, const float* __restrict__ gb_out,
                                              const float* __restrict__ lb_out, const float* __restrict__ fb,
                                              float* __restrict__ bias1, float* __restrict__ bias2) {
  __shared__ float bv[512];
  const int which = blockIdx.y;
  const int i0 = blockIdx.x * 64;
  const float* src = which ? lb_out : gb_out;
  for (int t = threadIdx.x; t < 512; t += 256) bv[t] = src[t];
  __syncthreads();
  const int r = threadIdx.x >> 2, c4 = threadIdx.x & 3;
  const float* frow = fw + (size_t)(i0 + r) * 1024 + (which ? 512 : 0) + c4 * 128;
  float a = 0.f;
  #pragma unroll 4
  for (int k = 0; k < 128; k += 4) {
    float4 v = *(const float4*)(frow + k);
    a += v.x * bv[c4 * 128 + k] + v.y * bv[c4 * 128 + k + 1]
       + v.z * bv[c4 * 128 + k + 2] + v.w * bv[c4 * 128 + k + 3];
  }
  a += __shfl_xor(a, 1);
  a += __shfl_xor(a, 2);
  if (c4 == 0) {
    int i = i0 + r;
    if (which) bias2[i] = a;
    else       bias1[i] = a + fb[i];
  }
}

// ---------------- bf16 GEMM v2: 128x128 tile, 2 waves x (128M x 64N), conflict-free swizzled LDS ----------------
// LDS layout per [128][32] tile: 16B chunk c of row r stored at in-row slot c ^ ((r>>1)&3).
// Frag reads hit each bank-group exactly twice (free); staging uses linear LDS dest +
// inverse-swizzled per-lane global source (global_load_lds wave-uniform-dest rule).
// EPI==0: QKV epilogue -> bf16 (acc+bias)*qs.  EPI==1: fp32 relu(accA+accA2+b1+c(p)*b2), dual source.
template <int EPI>
__global__ __launch_bounds__(128) void k_gemm2(const unsigned short* __restrict__ A,
                                               const unsigned short* __restrict__ A2,
                                               const unsigned short* __restrict__ Wm,
                                               const unsigned short* __restrict__ W2,
                                               const float* __restrict__ bias,
                                               const float* __restrict__ bias2,
                                               float qscale, void* __restrict__ Cout,
                                               int Ntot, int NT) {
  __shared__ unsigned short As[2][128 * 32];
  __shared__ unsigned short Bs[2][128 * 32];
  const int tid = threadIdx.x;
  const int wave = tid >> 6, lane = tid & 63;
  const int bm = blockIdx.x, bn = blockIdx.y;
  const int ql = lane & 15, kg = lane >> 4;

  auto stage = [&](int buf, int t) {
    const unsigned short* sA = A;
    const unsigned short* sW = Wm;
    int k0 = t * 32;
    if (EPI == 1 && t >= 16) { sA = A2; sW = W2; k0 = (t - 16) * 32; }
    #pragma unroll
    for (int i = 0; i < 4; i++) {
      int n = i * 128 + tid;          // linear 16B slot
      int row = n >> 2, s = n & 3;
      int c = s ^ ((row >> 1) & 3);   // inverse swizzle on the source
      gload16(sA + (size_t)(bm * 128 + row) * 512 + k0 + c * 8, &As[buf][n * 8]);
      gload16(sW + (size_t)(bn * 128 + row) * 512 + k0 + c * 8, &Bs[buf][n * 8]);
    }
  };

  // lane-constant slot term: slot(row=..+ql, chunk=kg) = kg ^ ((ql>>1)&3)
  const int offs = ql * 32 + ((kg ^ ((ql >> 1) & 3)) * 8);

  f32x4 acc[8][4] = {};
  stage(0, 0);
  __syncthreads();
  for (int t = 0; t < NT; t++) {
    int buf = t & 1;
    if (t + 1 < NT) stage(buf ^ 1, t + 1);
    const unsigned short* as = As[buf];
    const unsigned short* bs = Bs[buf] + wave * 2048;
    bf16x8 bfr[4];
    #pragma unroll
    for (int nq = 0; nq < 4; nq++)
      bfr[nq] = *(const bf16x8*)(bs + nq * 512 + offs);
    #pragma unroll
    for (int mq = 0; mq < 8; mq++) {
      bf16x8 af = *(const bf16x8*)(as + mq * 512 + offs);
      #pragma unroll
      for (int nq = 0; nq < 4; nq++)
        acc[mq][nq] = MFMA(af, bfr[nq], acc[mq][nq]);
    }
    __syncthreads();
  }

  const int row0 = bm * 128;
  const int col0 = bn * 128 + wave * 64;
  if (EPI == 0) {
    unsigned short* C = (unsigned short*)Cout;
    #pragma unroll
    for (int mq = 0; mq < 8; mq++)
      #pragma unroll
      for (int nq = 0; nq < 4; nq++) {
        int col = col0 + nq * 16 + ql;
        float bcol = bias[col];
        float qs = (col < 512) ? qscale : 1.0f;
        #pragma unroll
        for (int r = 0; r < 4; r++) {
          int row = row0 + mq * 16 + kg * 4 + r;
          C[(size_t)row * Ntot + col] = f2bf((acc[mq][nq][r] + bcol) * qs);
        }
      }
  } else {
    float* C = (float*)Cout;
    #pragma unroll
    for (int mq = 0; mq < 8; mq++)
      #pragma unroll
      for (int nq = 0; nq < 4; nq++) {
        int col = col0 + nq * 16 + ql;
        float b1 = bias[col], b2 = bias2[col];
        #pragma unroll
        for (int r = 0; r < 4; r++) {
          int row = row0 + mq * 16 + kg * 4 + r;
          float cc = ((row & 511) < 5) ? 1.0f : 2.0f;   // window coverage count
          float v = acc[mq][nq][r] + b1 + cc * b2;
          C[(size_t)row * 512 + col] = fmaxf(v, 0.0f);
        }
      }
  }
}

// ---------------- global attention v7: 16 waves (4/SIMD), 128KB LDS, in-register P ----------------
__global__ __launch_bounds__(1024, 4) void k_attn_g(const unsigned short* __restrict__ QKV,
                                                    unsigned short* __restrict__ Og) {
  __shared__ unsigned short Klds[512 * 64];   // [key][d], 16B chunk c at slot c^(key&7)
  __shared__ unsigned short Vt[64 * 512];     // [d][perm-key], 16B chunk c at slot c^(d&7)
  const int tid = threadIdx.x, wave = tid >> 6, lane = tid & 63;
  const int ql = lane & 15, kg = lane >> 4;
  const int h = blockIdx.x, b = blockIdx.y;
  const size_t tb = (size_t)b * 512;
  const size_t hoff = (size_t)h * 64;

  // stage K: 64 gload16 instrs, 4 per wave; source pre-swizzled
  #pragma unroll
  for (int i = 0; i < 4; i++) {
    int instr = wave * 4 + i;
    int row = instr * 8 + (lane >> 3);
    int slot = lane & 7;
    int c = slot ^ (row & 7);
    gload16(QKV + (tb + row) * 1536 + 512 + hoff + c * 8, &Klds[instr * 512 + lane * 8]);
  }
  // stage V^T: thread t -> key t&511, 4 of 8 d-chunks; column sigma-permuted within 64-key tile
  {
    int key = tid & 511;
    int cb = (tid >> 9) * 4;
    int k64 = key & 63;
    int f = k64 >> 4, kgv = (k64 >> 2) & 3, r = k64 & 3;
    int col = (key & ~63) + 32 * (f >> 1) + 4 * (f & 1) + 8 * kgv + r;
    const unsigned short* Vp = QKV + (tb + key) * 1536 + 1024 + hoff;
    #pragma unroll
    for (int c8 = 0; c8 < 4; c8++) {
      bf16x8 v8 = *(const bf16x8*)(Vp + (cb + c8) * 8);
      #pragma unroll
      for (int j = 0; j < 8; j++) {
        int d = (cb + c8) * 8 + j;
        Vt[d * 512 + (((col >> 3) ^ (d & 7)) * 8) + (col & 7)] = (unsigned short)v8[j];
      }
    }
  }
  // Q fragments: wave owns queries wave*32 + m*16 + ql; Q pre-scaled by (1/8)*log2(e)
  bf16x8 qf[2][2];
  #pragma unroll
  for (int m = 0; m < 2; m++) {
    const unsigned short* Qp = QKV + (tb + wave * 32 + m * 16 + ql) * 1536 + hoff;
    qf[m][0] = *(const bf16x8*)(Qp + kg * 8);
    qf[m][1] = *(const bf16x8*)(Qp + 32 + kg * 8);
  }
  __syncthreads();

  float l_part[2] = {};
  f32x4 ot[2][4] = {};

  for (int kv = 0; kv < 8; kv++) {
    const int k0 = kv * 64;
    bf16x8 kf[4][2], vb[4][2];
    #pragma unroll
    for (int f = 0; f < 4; f++) {
      int row = k0 + 16 * f + ql;
      #pragma unroll
      for (int c = 0; c < 2; c++)
        kf[f][c] = *(const bf16x8*)&Klds[row * 64 + (((c * 4 + kg) ^ (row & 7)) * 8)];
      int d = 16 * f + ql;
      #pragma unroll
      for (int st = 0; st < 2; st++) {
        int cb_r = (k0 >> 3) + st * 4 + kg;
        vb[f][st] = *(const bf16x8*)&Vt[d * 512 + ((cb_r ^ (d & 7)) * 8)];
      }
    }
    #pragma unroll
    for (int m = 0; m < 2; m++) {
      // S^T = K @ Q^T: lane holds keys 16f+4kg+{0..3} at col q=ql
      f32x4 s[4] = {};
      #pragma unroll
      for (int f = 0; f < 4; f++) {
        s[f] = MFMA(kf[f][0], qf[m][0], s[f]);
        s[f] = MFMA(kf[f][1], qf[m][1], s[f]);
      }
      #pragma unroll
      for (int f = 0; f < 4; f++) {
        #pragma unroll
        for (int r = 0; r < 4; r++)
          s[f][r] = exp2f(s[f][r]);
        l_part[m] += (s[f][0] + s[f][1]) + (s[f][2] + s[f][3]);
      }
      // PV (key-permuted): B-frag fully in-lane; O^T[d][q] += V^T @ P^T
      #pragma unroll
      for (int st = 0; st < 2; st++) {
        union { unsigned w[4]; bf16x8 v; } pb;
        #pragma unroll
        for (int w = 0; w < 4; w++) {
          int f = 2 * st + (w >> 1);
          pb.w[w] = cvtpk(s[f][2 * (w & 1)], s[f][2 * (w & 1) + 1]);
        }
        #pragma unroll
        for (int fp = 0; fp < 4; fp++)
          ot[m][fp] = MFMA(vb[fp][st], pb.v, ot[m][fp]);
      }
    }
  }

  // epilogue: divisor lane-uniform (q = ql); O^T rows d = 16*fp + 4*kg + reg
  #pragma unroll
  for (int m = 0; m < 2; m++) {
    float l = l_part[m];
    l += __shfl_xor(l, 16);
    l += __shfl_xor(l, 32);
    float inv = 1.0f / l;
    size_t row = tb + wave * 32 + m * 16 + ql;
    #pragma unroll
    for (int fp = 0; fp < 4; fp++) {
      ushort4 st4;
      st4.x = f2bf(ot[m][fp][0] * inv);
      st4.y = f2bf(ot[m][fp][1] * inv);
      st4.z = f2bf(ot[m][fp][2] * inv);
      st4.w = f2bf(ot[m][fp][3] * inv);
      *(ushort4*)&Og[row * 512 + hoff + 16 * fp + 4 * kg] = st4;
    }
  }
}

// ---------------- local windowed attention (all-lane phases) ----------------
__global__ __launch_bounds__(256) void k_attn_l(const unsigned short* __restrict__ QKV,
                                                unsigned short* __restrict__ Lacc) {
  __shared__ unsigned short Qs[5][520];
  __shared__ unsigned short Ks[15][520];
  __shared__ unsigned short Vs[15][520];
  __shared__ float Pb[2][4][5][13];
  const int w = blockIdx.x, b = blockIdx.y;
  const int p0 = 5 * w;
  const int tid = threadIdx.x;
  const size_t tbase = (size_t)b * 512;

  for (int c = tid; c < 35 * 64; c += 256) {
    int row = c >> 6, ch = (c & 63) * 8;
    if (row < 5) {
      int tok = min(p0 + row, 511);
      *(bf16x8*)&Qs[row][ch] = *(const bf16x8*)(QKV + (tbase + tok) * 1536 + ch);
    } else if (row < 20) {
      int rr = row - 5;
      int tok = min(max(p0 - 5 + rr, 0), 511);
      *(bf16x8*)&Ks[rr][ch] = *(const bf16x8*)(QKV + (tbase + tok) * 1536 + 512 + ch);
    } else {
      int rr = row - 20;
      int tok = min(max(p0 - 5 + rr, 0), 511);
      *(bf16x8*)&Vs[rr][ch] = *(const bf16x8*)(QKV + (tbase + tok) * 1536 + 1024 + ch);
    }
  }
  __syncthreads();

  #pragma unroll
  for (int rep = 0; rep < 2; rep++) {
    int idx = tid + rep * 256;
    if (idx < 400) {
      int j = idx % 10;
      int t1 = idx / 10;
      int q = t1 % 5;
      int t2 = t1 / 5;
      int h = t2 & 3;
      int win = t2 >> 2;
      int krow = win ? j : j + 5;
      int ktok = p0 - 5 + krow;
      float scv = -1e30f;
      bool ok = (win == 0 || w > 0) && (p0 + q < 512) && (ktok < 512);
      if (ok) {
        float acc = 0.f;
        const unsigned short* qp = &Qs[q][h * 128];
        const unsigned short* kp = &Ks[krow][h * 128];
        #pragma unroll
        for (int ck = 0; ck < 16; ck++) {
          bf16x8 q8 = *(const bf16x8*)(qp + ck * 8);
          bf16x8 k8 = *(const bf16x8*)(kp + ck * 8);
          #pragma unroll
          for (int e = 0; e < 8; e++)
            acc += bf2f((unsigned short)q8[e]) * bf2f((unsigned short)k8[e]);
        }
        scv = acc;
      }
      Pb[win][h][q][j] = scv;
    }
  }
  __syncthreads();

  if (tid < 40) {
    int q = tid % 5;
    int t2 = tid / 5;
    int h = t2 & 3;
    int win = t2 >> 2;
    float* row = &Pb[win][h][q][0];
    float mx = -1e30f;
    #pragma unroll
    for (int j = 0; j < 10; j++) mx = fmaxf(mx, row[j]);
    float e[10]; float su = 0.f;
    #pragma unroll
    for (int j = 0; j < 10; j++) {
      float v = row[j];
      float ej = (v <= -1e29f) ? 0.f : exp2f(v - mx);
      e[j] = ej; su += ej;
    }
    float inv = (su > 0.f) ? 1.0f / su : 0.f;
    #pragma unroll
    for (int j = 0; j < 10; j++) row[j] = e[j] * inv;
  }
  __syncthreads();

  {
    const int h = tid >> 6;
    const int d = tid * 2;
    for (int qq = 0; qq < 5; qq++) {
      int p = p0 + qq;
      if (p >= 512) break;
      float a0 = 0.f, a1 = 0.f;
      const float* P0 = &Pb[0][h][qq][0];
      #pragma unroll
      for (int j = 0; j < 10; j++) {
        float pw = P0[j];
        a0 += pw * bf2f(Vs[j + 5][d]);
        a1 += pw * bf2f(Vs[j + 5][d + 1]);
      }
      if (w > 0) {
        const float* P1 = &Pb[1][h][qq][0];
        #pragma unroll
        for (int j = 0; j < 10; j++) {
          float pw = P1[j];
          a0 += pw * bf2f(Vs[j][d]);
          a1 += pw * bf2f(Vs[j][d + 1]);
        }
      }
      ushort2 st; st.x = f2bf(a0); st.y = f2bf(a1);
      *(ushort2*)&Lacc[(tbase + p) * 512 + d] = st;
    }
  }
}

// ---------------- launcher ----------------
extern "C" void kernel_launch(void* const* d_in, const int* in_sizes, int n_in,
                              void* d_out, int out_size, void* d_ws, size_t ws_size,
                              hipStream_t stream) {
  const float* x      = (const float*)d_in[0];
  const float* gw_in  = (const float*)d_in[1];
  const float* gb_in  = (const float*)d_in[2];
  const float* gw_out = (const float*)d_in[3];
  const float* gb_out = (const float*)d_in[4];
  const float* lw_in  = (const float*)d_in[5];
  const float* lb_in  = (const float*)d_in[6];
  const float* lw_out = (const float*)d_in[7];
  const float* lb_out = (const float*)d_in[8];
  const float* fw     = (const float*)d_in[9];
  const float* fb     = (const float*)d_in[10];

  char* ws = (char*)d_ws;
  auto alloc = [&](size_t bytes) -> char* {
    char* p = ws;
    ws += (bytes + 255) & ~(size_t)255;
    return p;
  };
  unsigned short* xb     = (unsigned short*)alloc((size_t)16384 * 512 * 2);
  unsigned short* gwin_b = (unsigned short*)alloc((size_t)1536 * 512 * 2);
  unsigned short* lwin_b = (unsigned short*)alloc((size_t)1536 * 512 * 2);
  unsigned short* M1b    = (unsigned short*)alloc((size_t)512 * 512 * 2);
  unsigned short* M2b    = (unsigned short*)alloc((size_t)512 * 512 * 2);
  float* bias1           = (float*)alloc(512 * 4);
  float* bias2           = (float*)alloc(512 * 4);
  unsigned short* QKV    = (unsigned short*)alloc((size_t)16384 * 1536 * 2);
  unsigned short* Og     = (unsigned short*)alloc((size_t)16384 * 512 * 2);
  unsigned short* La     = (unsigned short*)alloc((size_t)16384 * 512 * 2);

  k_f2bf<<<2048, 256, 0, stream>>>(x, xb, 16384 * 512);
  k_f2bf<<<128, 256, 0, stream>>>(gw_in, gwin_b, 1536 * 512);
  k_f2bf<<<128, 256, 0, stream>>>(lw_in, lwin_b, 1536 * 512);
  k_merge<<<dim3(8, 8, 2), 256, 0, stream>>>(fw, gw_out, lw_out, M1b, M2b);
  k_bias<<<dim3(8, 2), 256, 0, stream>>>(fw, gb_out, lb_out, fb, bias1, bias2);

  // global QKV: Q pre-scaled by (1/8)*log2(e) so attention scores are in log2 units
  k_gemm2<0><<<dim3(128, 12), 128, 0, stream>>>(xb, nullptr, gwin_b, nullptr, gb_in, nullptr,
                                                0.125f * 1.44269504f, QKV, 1536, 16);
  k_attn_g<<<dim3(8, 32), 1024, 0, stream>>>(QKV, Og);

  // local QKV: Q pre-scaled by (1/sqrt(128))*log2(e)
  k_gemm2<0><<<dim3(128, 12), 128, 0, stream>>>(xb, nullptr, lwin_b, nullptr, lb_in, nullptr,
                                                0.08838834764831845f * 1.44269504f, QKV, 1536, 16);
  k_attn_l<<<dim3(103, 32), 256, 0, stream>>>(QKV, La);

  // fused final: relu(Og@M1^T + La@M2^T + bias1 + c(p)*bias2)
  k_gemm2<1><<<dim3(128, 4), 128, 0, stream>>>(Og, La, M1b, M2b, bias1, bias2,
                                               1.0f, d_out, 512, 32);
}

// Round 12
// 214.127 us; speedup vs baseline: 1.1792x; 1.1792x over previous
//
#include <hip/hip_runtime.h>
#include <cstdint>
#include <cstddef>

#define DEV __device__ __forceinline__

typedef float f32x4 __attribute__((ext_vector_type(4)));
typedef short bf16x8 __attribute__((ext_vector_type(8)));

DEV unsigned short f2bf(float f) {
  union { float f; unsigned u; } v; v.f = f;
  unsigned u = v.u;
  unsigned r = u + 0x7FFFu + ((u >> 16) & 1u);   // RNE
  return (unsigned short)(r >> 16);
}
DEV float bf2f(unsigned short h) {
  union { unsigned u; float f; } v; v.u = ((unsigned)h) << 16;
  return v.f;
}
DEV unsigned cvtpk(float lo, float hi) {         // 2 f32 -> packed 2x bf16 (RNE)
  unsigned r;
  asm("v_cvt_pk_bf16_f32 %0, %1, %2" : "=v"(r) : "v"(lo), "v"(hi));
  return r;
}

DEV void gload16(const void* g, void* l) {
  __builtin_amdgcn_global_load_lds((const __attribute__((address_space(1))) unsigned int*)g,
                                   (__attribute__((address_space(3))) unsigned int*)l,
                                   16, 0, 0);
}

DEV f32x4 MFMA(bf16x8 a, bf16x8 b, f32x4 c) {
  return __builtin_amdgcn_mfma_f32_16x16x32_bf16(a, b, c, 0, 0, 0);
}

// ---------------- fp32 -> bf16 convert ----------------
__global__ void k_f2bf(const float* __restrict__ src, unsigned short* __restrict__ dst, int n) {
  int i = (blockIdx.x * blockDim.x + threadIdx.x) * 4;
  int stride = gridDim.x * blockDim.x * 4;
  for (; i < n; i += stride) {
    float4 v = *(const float4*)(src + i);
    ushort4 o;
    o.x = f2bf(v.x); o.y = f2bf(v.y); o.z = f2bf(v.z); o.w = f2bf(v.w);
    *(ushort4*)(dst + i) = o;
  }
}

// ---------------- merged weights: M1 = fw[:, :512] @ gw_out ; M2 = fw[:, 512:] @ lw_out ----------------
__global__ __launch_bounds__(256) void k_merge(const float* __restrict__ fw,
                                               const float* __restrict__ gw_out,
                                               const float* __restrict__ lw_out,
                                               unsigned short* __restrict__ M1b,
                                               unsigned short* __restrict__ M2b) {
  __shared__ float Fa[64][68];
  __shared__ float Gb[64][68];
  const int bi = blockIdx.x, bj = blockIdx.y, m2 = blockIdx.z;
  const float* g = m2 ? lw_out : gw_out;
  const int i0 = bi * 64, j0 = bj * 64;
  const int tid = threadIdx.x;
  const int tr = tid >> 4, tc = tid & 15;
  float acc[4][4] = {};
  for (int kc = 0; kc < 8; kc++) {
    int k0 = kc * 64;
    __syncthreads();
    #pragma unroll
    for (int it = 0; it < 4; it++) {
      int r = tr + 16 * it;
      float4 v = *(const float4*)(fw + (size_t)(i0 + r) * 1024 + m2 * 512 + k0 + tc * 4);
      Fa[tc * 4 + 0][r] = v.x; Fa[tc * 4 + 1][r] = v.y;
      Fa[tc * 4 + 2][r] = v.z; Fa[tc * 4 + 3][r] = v.w;
      *(float4*)&Gb[r][tc * 4] = *(const float4*)(g + (size_t)(k0 + r) * 512 + j0 + tc * 4);
    }
    __syncthreads();
    for (int k = 0; k < 64; k++) {
      float4 a4 = *(const float4*)&Fa[k][tr * 4];
      float4 b4 = *(const float4*)&Gb[k][tc * 4];
      float av[4] = {a4.x, a4.y, a4.z, a4.w};
      float bv[4] = {b4.x, b4.y, b4.z, b4.w};
      #pragma unroll
      for (int r = 0; r < 4; r++)
        #pragma unroll
        for (int c = 0; c < 4; c++)
          acc[r][c] += av[r] * bv[c];
    }
  }
  unsigned short* M = m2 ? M2b : M1b;
  #pragma unroll
  for (int r = 0; r < 4; r++) {
    ushort4 pk;
    pk.x = f2bf(acc[r][0]); pk.y = f2bf(acc[r][1]);
    pk.z = f2bf(acc[r][2]); pk.w = f2bf(acc[r][3]);
    *(ushort4*)&M[(size_t)(i0 + tr * 4 + r) * 512 + j0 + tc * 4] = pk;
  }
}

// bias1 = fw1 @ gb_out + fb ; bias2 = fw2 @ lb_out.  grid (8,2), 64 outputs/block.
__global__ __launch_bounds__(256) void k_bias(const float* __restrict__ fw, const float* __restrict__ gb_out,
                                              const float* __restrict__ lb_out, const float* __restrict__ fb,
                                              float* __restrict__ bias1, float* __restrict__ bias2) {
  __shared__ float bv[512];
  const int which = blockIdx.y;
  const int i0 = blockIdx.x * 64;
  const float* src = which ? lb_out : gb_out;
  for (int t = threadIdx.x; t < 512; t += 256) bv[t] = src[t];
  __syncthreads();
  const int r = threadIdx.x >> 2, c4 = threadIdx.x & 3;
  const float* frow = fw + (size_t)(i0 + r) * 1024 + (which ? 512 : 0) + c4 * 128;
  float a = 0.f;
  #pragma unroll 4
  for (int k = 0; k < 128; k += 4) {
    float4 v = *(const float4*)(frow + k);
    a += v.x * bv[c4 * 128 + k] + v.y * bv[c4 * 128 + k + 1]
       + v.z * bv[c4 * 128 + k + 2] + v.w * bv[c4 * 128 + k + 3];
  }
  a += __shfl_xor(a, 1);
  a += __shfl_xor(a, 2);
  if (c4 == 0) {
    int i = i0 + r;
    if (which) bias2[i] = a;
    else       bias1[i] = a + fb[i];
  }
}

// ---------------- bf16 GEMM: 128x128 tile, 4 waves, BK=32, dbuf global_load_lds ----------------
// Conflict-free LDS: within each 64B row, 16B slot s holds global chunk s ^ ((row>>1)&3).
// Staged with linear LDS dest + inverse-swizzled per-lane SOURCE chunk (both-sides rule).
// Frag-read slot term (kg ^ ((ql>>1)&3)) is lane-constant -> zero extra VALU in the loop;
// each 8-consecutive-lane LDS group covers all 8 16B positions of a 128B line (0 conflicts).
template <int EPI>
__global__ __launch_bounds__(256) void k_gemm(const unsigned short* __restrict__ A,
                                              const unsigned short* __restrict__ A2,
                                              const unsigned short* __restrict__ Wm,
                                              const unsigned short* __restrict__ W2,
                                              const float* __restrict__ bias,
                                              const float* __restrict__ bias2,
                                              float qscale, void* __restrict__ Cout,
                                              int Ntot, int NT) {
  __shared__ unsigned short As[2][128 * 32];
  __shared__ unsigned short Bs[2][128 * 32];
  const int tid = threadIdx.x;
  const int wave = tid >> 6, lane = tid & 63;
  const int wr = wave >> 1, wc = wave & 1;
  const int bm = blockIdx.x, bn = blockIdx.y;
  const int ql = lane & 15, kg = lane >> 4;

  const int c0 = wave * 2;
  const int srow = lane >> 2;
  const int schunk = (lane & 3) ^ ((lane >> 3) & 3);   // inverse swizzle on the SOURCE

  auto stage = [&](int buf, int t) {
    const unsigned short* sA = A;
    const unsigned short* sW = Wm;
    int k0 = t * 32;
    if (EPI == 1 && t >= 16) { sA = A2; sW = W2; k0 = (t - 16) * 32; }
    #pragma unroll
    for (int i = 0; i < 2; i++) {
      int c = c0 + i;
      int row = c * 16 + srow;
      gload16(sA + (size_t)(bm * 128 + row) * 512 + k0 + schunk * 8, &As[buf][c * 512 + lane * 8]);
      gload16(sW + (size_t)(bn * 128 + row) * 512 + k0 + schunk * 8, &Bs[buf][c * 512 + lane * 8]);
    }
  };

  const int soff = (kg ^ ((ql >> 1) & 3)) * 8;   // lane-constant swizzled slot

  f32x4 acc[4][4] = {};
  stage(0, 0);
  __syncthreads();
  for (int t = 0; t < NT; t++) {
    int buf = t & 1;
    if (t + 1 < NT) stage(buf ^ 1, t + 1);
    const unsigned short* as = As[buf];
    const unsigned short* bs = Bs[buf];
    bf16x8 af[4], bfr[4];
    #pragma unroll
    for (int m = 0; m < 4; m++)
      af[m] = *(const bf16x8*)&as[(wr * 64 + m * 16 + ql) * 32 + soff];
    #pragma unroll
    for (int n = 0; n < 4; n++)
      bfr[n] = *(const bf16x8*)&bs[(wc * 64 + n * 16 + ql) * 32 + soff];
    #pragma unroll
    for (int m = 0; m < 4; m++)
      #pragma unroll
      for (int n = 0; n < 4; n++)
        acc[m][n] = MFMA(af[m], bfr[n], acc[m][n]);
    __syncthreads();
  }

  const int row0 = bm * 128 + wr * 64;
  const int col0 = bn * 128 + wc * 64;
  if (EPI == 0) {
    unsigned short* C = (unsigned short*)Cout;
    #pragma unroll
    for (int m = 0; m < 4; m++)
      #pragma unroll
      for (int n = 0; n < 4; n++) {
        int col = col0 + n * 16 + ql;
        float bcol = bias[col];
        float qs = (col < 512) ? qscale : 1.0f;
        #pragma unroll
        for (int r = 0; r < 4; r++) {
          int row = row0 + m * 16 + kg * 4 + r;
          C[(size_t)row * Ntot + col] = f2bf((acc[m][n][r] + bcol) * qs);
        }
      }
  } else {
    float* C = (float*)Cout;
    #pragma unroll
    for (int m = 0; m < 4; m++)
      #pragma unroll
      for (int n = 0; n < 4; n++) {
        int col = col0 + n * 16 + ql;
        float b1 = bias[col], b2 = bias2[col];
        #pragma unroll
        for (int r = 0; r < 4; r++) {
          int row = row0 + m * 16 + kg * 4 + r;
          float cc = ((row & 511) < 5) ? 1.0f : 2.0f;   // window coverage count
          float v = acc[m][n][r] + b1 + cc * b2;
          C[(size_t)row * 512 + col] = fmaxf(v, 0.0f);
        }
      }
  }
}

// ---------------- global attention v7: 16 waves (4/SIMD), 128KB LDS, in-register P ----------------
__global__ __launch_bounds__(1024, 4) void k_attn_g(const unsigned short* __restrict__ QKV,
                                                    unsigned short* __restrict__ Og) {
  __shared__ unsigned short Klds[512 * 64];   // [key][d], 16B chunk c at slot c^(key&7)
  __shared__ unsigned short Vt[64 * 512];     // [d][perm-key], 16B chunk c at slot c^(d&7)
  const int tid = threadIdx.x, wave = tid >> 6, lane = tid & 63;
  const int ql = lane & 15, kg = lane >> 4;
  const int h = blockIdx.x, b = blockIdx.y;
  const size_t tb = (size_t)b * 512;
  const size_t hoff = (size_t)h * 64;

  // stage K: 64 gload16 instrs, 4 per wave; source pre-swizzled
  #pragma unroll
  for (int i = 0; i < 4; i++) {
    int instr = wave * 4 + i;
    int row = instr * 8 + (lane >> 3);
    int slot = lane & 7;
    int c = slot ^ (row & 7);
    gload16(QKV + (tb + row) * 1536 + 512 + hoff + c * 8, &Klds[instr * 512 + lane * 8]);
  }
  // stage V^T: thread t -> key t&511, 4 of 8 d-chunks; column sigma-permuted within 64-key tile
  {
    int key = tid & 511;
    int cb = (tid >> 9) * 4;
    int k64 = key & 63;
    int f = k64 >> 4, kgv = (k64 >> 2) & 3, r = k64 & 3;
    int col = (key & ~63) + 32 * (f >> 1) + 4 * (f & 1) + 8 * kgv + r;
    const unsigned short* Vp = QKV + (tb + key) * 1536 + 1024 + hoff;
    #pragma unroll
    for (int c8 = 0; c8 < 4; c8++) {
      bf16x8 v8 = *(const bf16x8*)(Vp + (cb + c8) * 8);
      #pragma unroll
      for (int j = 0; j < 8; j++) {
        int d = (cb + c8) * 8 + j;
        Vt[d * 512 + (((col >> 3) ^ (d & 7)) * 8) + (col & 7)] = (unsigned short)v8[j];
      }
    }
  }
  // Q fragments: wave owns queries wave*32 + m*16 + ql; Q pre-scaled by (1/8)*log2(e)
  bf16x8 qf[2][2];
  #pragma unroll
  for (int m = 0; m < 2; m++) {
    const unsigned short* Qp = QKV + (tb + wave * 32 + m * 16 + ql) * 1536 + hoff;
    qf[m][0] = *(const bf16x8*)(Qp + kg * 8);
    qf[m][1] = *(const bf16x8*)(Qp + 32 + kg * 8);
  }
  __syncthreads();

  float l_part[2] = {};
  f32x4 ot[2][4] = {};

  for (int kv = 0; kv < 8; kv++) {
    const int k0 = kv * 64;
    bf16x8 kf[4][2], vb[4][2];
    #pragma unroll
    for (int f = 0; f < 4; f++) {
      int row = k0 + 16 * f + ql;
      #pragma unroll
      for (int c = 0; c < 2; c++)
        kf[f][c] = *(const bf16x8*)&Klds[row * 64 + (((c * 4 + kg) ^ (row & 7)) * 8)];
      int d = 16 * f + ql;
      #pragma unroll
      for (int st = 0; st < 2; st++) {
        int cb_r = (k0 >> 3) + st * 4 + kg;
        vb[f][st] = *(const bf16x8*)&Vt[d * 512 + ((cb_r ^ (d & 7)) * 8)];
      }
    }
    #pragma unroll
    for (int m = 0; m < 2; m++) {
      // S^T = K @ Q^T: lane holds keys 16f+4kg+{0..3} at col q=ql
      f32x4 s[4] = {};
      #pragma unroll
      for (int f = 0; f < 4; f++) {
        s[f] = MFMA(kf[f][0], qf[m][0], s[f]);
        s[f] = MFMA(kf[f][1], qf[m][1], s[f]);
      }
      #pragma unroll
      for (int f = 0; f < 4; f++) {
        #pragma unroll
        for (int r = 0; r < 4; r++)
          s[f][r] = exp2f(s[f][r]);
        l_part[m] += (s[f][0] + s[f][1]) + (s[f][2] + s[f][3]);
      }
      // PV (key-permuted): B-frag fully in-lane; O^T[d][q] += V^T @ P^T
      #pragma unroll
      for (int st = 0; st < 2; st++) {
        union { unsigned w[4]; bf16x8 v; } pb;
        #pragma unroll
        for (int w = 0; w < 4; w++) {
          int f = 2 * st + (w >> 1);
          pb.w[w] = cvtpk(s[f][2 * (w & 1)], s[f][2 * (w & 1) + 1]);
        }
        #pragma unroll
        for (int fp = 0; fp < 4; fp++)
          ot[m][fp] = MFMA(vb[fp][st], pb.v, ot[m][fp]);
      }
    }
  }

  // epilogue: divisor lane-uniform (q = ql); O^T rows d = 16*fp + 4*kg + reg
  #pragma unroll
  for (int m = 0; m < 2; m++) {
    float l = l_part[m];
    l += __shfl_xor(l, 16);
    l += __shfl_xor(l, 32);
    float inv = 1.0f / l;
    size_t row = tb + wave * 32 + m * 16 + ql;
    #pragma unroll
    for (int fp = 0; fp < 4; fp++) {
      ushort4 st4;
      st4.x = f2bf(ot[m][fp][0] * inv);
      st4.y = f2bf(ot[m][fp][1] * inv);
      st4.z = f2bf(ot[m][fp][2] * inv);
      st4.w = f2bf(ot[m][fp][3] * inv);
      *(ushort4*)&Og[row * 512 + hoff + 16 * fp + 4 * kg] = st4;
    }
  }
}

// ---------------- local windowed attention (all-lane phases) ----------------
__global__ __launch_bounds__(256) void k_attn_l(const unsigned short* __restrict__ QKV,
                                                unsigned short* __restrict__ Lacc) {
  __shared__ unsigned short Qs[5][520];
  __shared__ unsigned short Ks[15][520];
  __shared__ unsigned short Vs[15][520];
  __shared__ float Pb[2][4][5][13];
  const int w = blockIdx.x, b = blockIdx.y;
  const int p0 = 5 * w;
  const int tid = threadIdx.x;
  const size_t tbase = (size_t)b * 512;

  for (int c = tid; c < 35 * 64; c += 256) {
    int row = c >> 6, ch = (c & 63) * 8;
    if (row < 5) {
      int tok = min(p0 + row, 511);
      *(bf16x8*)&Qs[row][ch] = *(const bf16x8*)(QKV + (tbase + tok) * 1536 + ch);
    } else if (row < 20) {
      int rr = row - 5;
      int tok = min(max(p0 - 5 + rr, 0), 511);
      *(bf16x8*)&Ks[rr][ch] = *(const bf16x8*)(QKV + (tbase + tok) * 1536 + 512 + ch);
    } else {
      int rr = row - 20;
      int tok = min(max(p0 - 5 + rr, 0), 511);
      *(bf16x8*)&Vs[rr][ch] = *(const bf16x8*)(QKV + (tbase + tok) * 1536 + 1024 + ch);
    }
  }
  __syncthreads();

  #pragma unroll
  for (int rep = 0; rep < 2; rep++) {
    int idx = tid + rep * 256;
    if (idx < 400) {
      int j = idx % 10;
      int t1 = idx / 10;
      int q = t1 % 5;
      int t2 = t1 / 5;
      int h = t2 & 3;
      int win = t2 >> 2;
      int krow = win ? j : j + 5;
      int ktok = p0 - 5 + krow;
      float scv = -1e30f;
      bool ok = (win == 0 || w > 0) && (p0 + q < 512) && (ktok < 512);
      if (ok) {
        float acc = 0.f;
        const unsigned short* qp = &Qs[q][h * 128];
        const unsigned short* kp = &Ks[krow][h * 128];
        #pragma unroll
        for (int ck = 0; ck < 16; ck++) {
          bf16x8 q8 = *(const bf16x8*)(qp + ck * 8);
          bf16x8 k8 = *(const bf16x8*)(kp + ck * 8);
          #pragma unroll
          for (int e = 0; e < 8; e++)
            acc += bf2f((unsigned short)q8[e]) * bf2f((unsigned short)k8[e]);
        }
        scv = acc;
      }
      Pb[win][h][q][j] = scv;
    }
  }
  __syncthreads();

  if (tid < 40) {
    int q = tid % 5;
    int t2 = tid / 5;
    int h = t2 & 3;
    int win = t2 >> 2;
    float* row = &Pb[win][h][q][0];
    float mx = -1e30f;
    #pragma unroll
    for (int j = 0; j < 10; j++) mx = fmaxf(mx, row[j]);
    float e[10]; float su = 0.f;
    #pragma unroll
    for (int j = 0; j < 10; j++) {
      float v = row[j];
      float ej = (v <= -1e29f) ? 0.f : exp2f(v - mx);
      e[j] = ej; su += ej;
    }
    float inv = (su > 0.f) ? 1.0f / su : 0.f;
    #pragma unroll
    for (int j = 0; j < 10; j++) row[j] = e[j] * inv;
  }
  __syncthreads();

  {
    const int h = tid >> 6;
    const int d = tid * 2;
    for (int qq = 0; qq < 5; qq++) {
      int p = p0 + qq;
      if (p >= 512) break;
      float a0 = 0.f, a1 = 0.f;
      const float* P0 = &Pb[0][h][qq][0];
      #pragma unroll
      for (int j = 0; j < 10; j++) {
        float pw = P0[j];
        a0 += pw * bf2f(Vs[j + 5][d]);
        a1 += pw * bf2f(Vs[j + 5][d + 1]);
      }
      if (w > 0) {
        const float* P1 = &Pb[1][h][qq][0];
        #pragma unroll
        for (int j = 0; j < 10; j++) {
          float pw = P1[j];
          a0 += pw * bf2f(Vs[j][d]);
          a1 += pw * bf2f(Vs[j][d + 1]);
        }
      }
      ushort2 st; st.x = f2bf(a0); st.y = f2bf(a1);
      *(ushort2*)&Lacc[(tbase + p) * 512 + d] = st;
    }
  }
}

// ---------------- launcher ----------------
extern "C" void kernel_launch(void* const* d_in, const int* in_sizes, int n_in,
                              void* d_out, int out_size, void* d_ws, size_t ws_size,
                              hipStream_t stream) {
  const float* x      = (const float*)d_in[0];
  const float* gw_in  = (const float*)d_in[1];
  const float* gb_in  = (const float*)d_in[2];
  const float* gw_out = (const float*)d_in[3];
  const float* gb_out = (const float*)d_in[4];
  const float* lw_in  = (const float*)d_in[5];
  const float* lb_in  = (const float*)d_in[6];
  const float* lw_out = (const float*)d_in[7];
  const float* lb_out = (const float*)d_in[8];
  const float* fw     = (const float*)d_in[9];
  const float* fb     = (const float*)d_in[10];

  char* ws = (char*)d_ws;
  auto alloc = [&](size_t bytes) -> char* {
    char* p = ws;
    ws += (bytes + 255) & ~(size_t)255;
    return p;
  };
  unsigned short* xb     = (unsigned short*)alloc((size_t)16384 * 512 * 2);
  unsigned short* gwin_b = (unsigned short*)alloc((size_t)1536 * 512 * 2);
  unsigned short* lwin_b = (unsigned short*)alloc((size_t)1536 * 512 * 2);
  unsigned short* M1b    = (unsigned short*)alloc((size_t)512 * 512 * 2);
  unsigned short* M2b    = (unsigned short*)alloc((size_t)512 * 512 * 2);
  float* bias1           = (float*)alloc(512 * 4);
  float* bias2           = (float*)alloc(512 * 4);
  unsigned short* QKV    = (unsigned short*)alloc((size_t)16384 * 1536 * 2);
  unsigned short* Og     = (unsigned short*)alloc((size_t)16384 * 512 * 2);
  unsigned short* La     = (unsigned short*)alloc((size_t)16384 * 512 * 2);

  k_f2bf<<<2048, 256, 0, stream>>>(x, xb, 16384 * 512);
  k_f2bf<<<128, 256, 0, stream>>>(gw_in, gwin_b, 1536 * 512);
  k_f2bf<<<128, 256, 0, stream>>>(lw_in, lwin_b, 1536 * 512);
  k_merge<<<dim3(8, 8, 2), 256, 0, stream>>>(fw, gw_out, lw_out, M1b, M2b);
  k_bias<<<dim3(8, 2), 256, 0, stream>>>(fw, gb_out, lb_out, fb, bias1, bias2);

  // global QKV: Q pre-scaled by (1/8)*log2(e) so attention scores are in log2 units
  k_gemm<0><<<dim3(128, 12), 256, 0, stream>>>(xb, nullptr, gwin_b, nullptr, gb_in, nullptr,
                                               0.125f * 1.44269504f, QKV, 1536, 16);
  k_attn_g<<<dim3(8, 32), 1024, 0, stream>>>(QKV, Og);

  // local QKV: Q pre-scaled by (1/sqrt(128))*log2(e)
  k_gemm<0><<<dim3(128, 12), 256, 0, stream>>>(xb, nullptr, lwin_b, nullptr, lb_in, nullptr,
                                               0.08838834764831845f * 1.44269504f, QKV, 1536, 16);
  k_attn_l<<<dim3(103, 32), 256, 0, stream>>>(QKV, La);

  // fused final: relu(Og@M1^T + La@M2^T + bias1 + c(p)*bias2)
  k_gemm<1><<<dim3(128, 4), 256, 0, stream>>>(Og, La, M1b, M2b, bias1, bias2,
                                              1.0f, d_out, 512, 32);
}